// Round 1
// baseline (86.775 us; speedup 1.0000x reference)
//
#include <hip/hip_runtime.h>

// out[b,n] = 1/(16*50625) * sum_j Acoeff[n,j] * S[b,j]
// S[b,j]   = sum_n Bbasis[j,n] * (M @ T[b,j])[n]
// T[b,j,m] = sum_{p,q,r,s} w[j1][p] w[j2][q] w[j3][r] w[j4][s] * arr[b,p,q,r,s,m]
// w masks (per dim, D=16, L=3, window R=2, stride 1, VALID):
//   class0: 0x36DB  class1: 0x6DB6  class2: 0xDB6C

static __device__ __forceinline__ void add4(float4& a, const float4& b) {
    a.x += b.x; a.y += b.y; a.z += b.z; a.w += b.w;
}
static __device__ __forceinline__ void fma4(float4& a, float w, const float4& b) {
    a.x = fmaf(w, b.x, a.x); a.y = fmaf(w, b.y, a.y);
    a.z = fmaf(w, b.z, a.z); a.w = fmaf(w, b.w, a.w);
}

__global__ __launch_bounds__(128) void sdd4_stage1(
    const float* __restrict__ arr,
    const float* __restrict__ Mmat,
    const float* __restrict__ Bbasis,
    float* __restrict__ S)
{
    __shared__ float4 U_lds[400];        // [r*25 + j4*8 + mv]  (pad 24->25 to avoid b128 bank conflicts)
    __shared__ float  V_lds[9 * 33];     // [jj*33 + m]
    __shared__ float  Y_lds[9 * 33];     // [jj*33 + n]
    __shared__ float  M_lds[32 * 33];    // [n*33 + m]
    __shared__ float  B_lds[81 * 33];    // [j*33 + n]

    const int t  = threadIdx.x;
    const int bx = blockIdx.x;           // 0..1023
    const int b  = bx >> 8;
    const int p  = (bx >> 4) & 15;
    const int q  = bx & 15;

    // ---- stage M (32x32) and Bbasis (81x32) into padded LDS ----
    const float4* M4 = reinterpret_cast<const float4*>(Mmat);
    for (int i = t; i < 256; i += 128) {
        float4 v = M4[i];
        float* dst = &M_lds[(i >> 3) * 33 + (i & 7) * 4];
        dst[0] = v.x; dst[1] = v.y; dst[2] = v.z; dst[3] = v.w;
    }
    const float4* B4 = reinterpret_cast<const float4*>(Bbasis);
    for (int i = t; i < 648; i += 128) {
        float4 v = B4[i];
        float* dst = &B_lds[(i >> 3) * 33 + (i & 7) * 4];
        dst[0] = v.x; dst[1] = v.y; dst[2] = v.z; dst[3] = v.w;
    }

    // ---- main global read: tile arr[b,p,q,:,:,:], reduce over s per class ----
    const int r  = t >> 3;               // 0..15
    const int mv = t & 7;                // float4 index within m (0..7)
    const float4* A4 = reinterpret_cast<const float4*>(arr);
    const size_t tile = (size_t)((b * 16 + p) * 16 + q) * 2048;  // 16*16*8 float4

    float4 u0 = make_float4(0.f, 0.f, 0.f, 0.f), u1 = u0, u2 = u0;
    #pragma unroll
    for (int s = 0; s < 16; ++s) {
        float4 x = A4[tile + (size_t)(r * 16 + s) * 8 + mv];
        if ((0x36DBu >> s) & 1) add4(u0, x);
        if ((0x6DB6u >> s) & 1) add4(u1, x);
        if ((0xDB6Cu >> s) & 1) add4(u2, x);
    }
    U_lds[r * 25 +      mv] = u0;
    U_lds[r * 25 +  8 + mv] = u1;
    U_lds[r * 25 + 16 + mv] = u2;
    __syncthreads();

    // ---- reduce over r per class: V[j3][j4][m] ----
    if (t < 72) {
        const int j3  = t / 24;
        const int rem = t % 24;
        const int j4  = rem >> 3;
        const int mv2 = rem & 7;
        const unsigned msk = (j3 == 0) ? 0x36DBu : (j3 == 1 ? 0x6DB6u : 0xDB6Cu);
        float4 acc = make_float4(0.f, 0.f, 0.f, 0.f);
        #pragma unroll
        for (int rr = 0; rr < 16; ++rr) {
            float w = (float)((msk >> rr) & 1u);
            fma4(acc, w, U_lds[rr * 25 + j4 * 8 + mv2]);
        }
        const int jj = j3 * 3 + j4;
        float* dv = &V_lds[jj * 33 + mv2 * 4];
        dv[0] = acc.x; dv[1] = acc.y; dv[2] = acc.z; dv[3] = acc.w;
    }
    __syncthreads();

    // ---- Y[jj][n] = sum_m M[n][m] * V[jj][m]   (9 matvecs of 32x32) ----
    for (int o = t; o < 288; o += 128) {
        const int jj = o >> 5;
        const int n  = o & 31;
        float acc = 0.f;
        #pragma unroll
        for (int m = 0; m < 32; ++m)
            acc = fmaf(M_lds[n * 33 + m], V_lds[jj * 33 + m], acc);
        Y_lds[jj * 33 + n] = acc;
    }
    __syncthreads();

    // ---- per-(j1,j2) combos for this (p,q): dot with Bbasis row, atomic into S ----
    int l1_0, l1_1 = 0, n1;
    if      (p == 0)  { l1_0 = 0; n1 = 1; }
    else if (p == 15) { l1_0 = 2; n1 = 1; }
    else              { l1_0 = (p - 1) % 3; l1_1 = p % 3; n1 = 2; }
    int l2_0, l2_1 = 0, n2;
    if      (q == 0)  { l2_0 = 0; n2 = 1; }
    else if (q == 15) { l2_0 = 2; n2 = 1; }
    else              { l2_0 = (q - 1) % 3; l2_1 = q % 3; n2 = 2; }

    const int ncomb = n1 * n2 * 9;
    if (t < ncomb) {
        const int jj  = t % 9;           // j3*3 + j4
        const int c12 = t / 9;
        const int i1idx = (n2 == 2) ? (c12 >> 1) : c12;
        const int i2idx = (n2 == 2) ? (c12 & 1)  : 0;
        const int i1 = i1idx ? l1_1 : l1_0;
        const int i2 = i2idx ? l2_1 : l2_0;
        const int jf = (i1 * 3 + i2) * 9 + jj;
        float acc = 0.f;
        #pragma unroll
        for (int n = 0; n < 32; ++n)
            acc = fmaf(Y_lds[jj * 33 + n], B_lds[jf * 33 + n], acc);
        atomicAdd(&S[b * 81 + jf], acc);
    }
}

__global__ __launch_bounds__(128) void sdd4_stage2(
    const float* __restrict__ S,
    const float* __restrict__ Acoeff,
    float* __restrict__ out)
{
    const int t = threadIdx.x;           // 128 = 4 b * 32 n
    const int b = t >> 5;
    const int n = t & 31;
    float acc = 0.f;
    #pragma unroll
    for (int j = 0; j < 81; ++j)
        acc = fmaf(Acoeff[n * 81 + j], S[b * 81 + j], acc);
    out[b * 32 + n] = acc * (1.0f / 810000.0f);   // 1/(16 * 15^4)
}

extern "C" void kernel_launch(void* const* d_in, const int* in_sizes, int n_in,
                              void* d_out, int out_size, void* d_ws, size_t ws_size,
                              hipStream_t stream) {
    const float* arr    = (const float*)d_in[0];  // [4,16,16,16,16,32]
    const float* Mmat   = (const float*)d_in[1];  // [32,32]
    const float* Acoeff = (const float*)d_in[2];  // [32,81]
    const float* Bbasis = (const float*)d_in[3];  // [81,32]
    float* S = (float*)d_ws;                      // 4*81 floats

    hipMemsetAsync(d_ws, 0, 4 * 81 * sizeof(float), stream);
    sdd4_stage1<<<dim3(1024), dim3(128), 0, stream>>>(arr, Mmat, Bbasis, S);
    sdd4_stage2<<<dim3(1), dim3(128), 0, stream>>>(S, Acoeff, (float*)d_out);
}